// Round 10
// baseline (915.731 us; speedup 1.0000x reference)
//
#include <hip/hip_runtime.h>

#define DZ 64
#define DX 32
#define DS 16
#define TT 1024
#define NS 1024

// LDS layout (floats). Staging region is CLOBBERED by the per-step
// broadcast arrays: weight re-reads from LDS become illegal after the
// first loop store -> weights MUST stay in registers.
#define AW_B 0                    // 64 rows * 65
#define C_B  (AW_B + DZ * (DZ + 1))      // 64 * 17
#define B_B  (C_B + DZ * (DS + 1))      // 32 * 65
#define SMEM_FLOATS (B_B + DX * (DZ + 1))
// runtime arrays overlap the staging region (intentional aliasing):
#define ZR_B 0                    // raw z     [4][64]
#define ZA_B 1024                 // relu z    [4][64]
#define U_B  2048                 // u         [4][16]

// Force the multiply operands into arch-VGPRs: constraint "v" is the VGPR
// class (AGPR is "a"). R8 diagnosis: allocator parked the 112 weight values
// in AGPRs and bounced each use through v_accvgpr_read (+224 VALU cyc/step,
// VGPR_Count=124 < live set). With every use "v"-constrained, the weight
// live ranges must be VGPR-allocated. Non-volatile: scheduler stays free.
#define FMA_ASM(acc, a, b) \
    asm("v_fma_f32 %0, %1, %2, %0" : "+v"(acc) : "v"(a), "v"(b))

__device__ __forceinline__ float softplus_eps(float x) {
    // jax.nn.softplus = max(x,0) + log1p(exp(-|x|)); +1e-6
    return fmaxf(x, 0.f) + log1pf(expf(-fabsf(x))) + 1e-6f;
}

__global__ __launch_bounds__(256, 1) void plrnn_fused_kernel(
    const float* __restrict__ u,   // (T, N, 16)
    const float* __restrict__ z0,  // (N, 64)
    const float* __restrict__ nz,  // (T, N, 64)
    const float* __restrict__ nx,  // (T, N, 32)
    const float* __restrict__ AW,  // (64, 64)
    const float* __restrict__ Cm,  // (64, 16)
    const float* __restrict__ Bm,  // (32, 64)
    const float* __restrict__ Q,   // (64,)
    const float* __restrict__ R,   // (32,)
    float* __restrict__ zo,        // (T, N, 64)
    float* __restrict__ xo)        // (T, N, 32)
{
    const int tid  = threadIdx.x;
    const int lane = tid & 63;
    const int wv   = tid >> 6;
    const int p    = lane & 31;          // x output row
    const int kb   = (lane >> 5) << 5;   // k-half base: 0 or 32
    const int sim  = __builtin_amdgcn_readfirstlane((int)((blockIdx.x << 2) | wv));

    __shared__ float smem[SMEM_FLOATS];

    {   // one-time stage: AW 16/thr, C 4/thr, B 8/thr
        const int r = tid >> 2;
        const int c = (tid & 3) * 16;
        #pragma unroll
        for (int k = 0; k < 16; ++k) smem[AW_B + r * (DZ + 1) + c + k] = AW[r * DZ + c + k];
        const int cc = (tid & 3) * 4;
        #pragma unroll
        for (int k = 0; k < 4; ++k) smem[C_B + r * (DS + 1) + cc + k] = Cm[r * DS + cc + k];
        const int br = tid >> 3;
        const int bc = (tid & 7) * 8;
        #pragma unroll
        for (int k = 0; k < 8; ++k) smem[B_B + br * (DZ + 1) + bc + k] = Bm[br * DZ + bc + k];
    }
    __syncthreads();

    // per-lane weights -> registers (compile-time indices only)
    float Wrow[DZ];
    float Ad = 0.f;
    #pragma unroll
    for (int k = 0; k < DZ; ++k) {
        const float w = smem[AW_B + lane * (DZ + 1) + k];
        Wrow[k] = (k == lane) ? 0.f : w;    // zero diagonal
        Ad      = (k == lane) ? w   : Ad;   // capture diagonal
    }
    float Crow[DS];
    #pragma unroll
    for (int s = 0; s < DS; ++s) Crow[s] = smem[C_B + lane * (DS + 1) + s];
    float Brow[32];                          // B[p][kb .. kb+31] (split-k)
    #pragma unroll
    for (int k = 0; k < 32; ++k) Brow[k] = smem[B_B + p * (DZ + 1) + kb + k];

    const float qv = softplus_eps(Q[lane]);
    const float rv = softplus_eps(R[p]);

    __syncthreads();   // all waves done reading staged weights before clobber

    float zl = z0[(size_t)sim * DZ + lane];

    const size_t snz = (size_t)NS * DZ;
    const size_t snx = (size_t)NS * DX;
    const size_t su  = (size_t)NS * DS;

    const float* pnz = nz + (size_t)sim * DZ + lane;
    const float* pnx = nx + (size_t)sim * DX + p;          // hi half dups low
    const float* puu = u  + (size_t)sim * DS + (lane & 15);
    float* pz = zo + (size_t)sim * DZ + lane;
    float* px = xo + (size_t)sim * DX + p;

    // prefetch depth 4, then running pointers (no per-step index muls)
    float nzb[4], nxb[4], ub[4];
    #pragma unroll
    for (int j = 0; j < 4; ++j) {
        nzb[j] = pnz[(size_t)j * snz];
        nxb[j] = pnx[(size_t)j * snx];
        ub[j]  = puu[(size_t)j * su];
    }
    const float* pnz_pf = pnz + 4 * snz;
    const float* pnx_pf = pnx + 4 * snx;
    const float* puu_pf = puu + 4 * su;

    float* lzr = &smem[ZR_B + wv * DZ];   // wave-private slices
    float* lza = &smem[ZA_B + wv * DZ];
    float* lup = &smem[U_B  + wv * DS];

    for (int t0 = 0; t0 < TT; t0 += 4) {
        #pragma unroll
        for (int j = 0; j < 4; ++j) {
            const int t = t0 + j;
            const float vnz = nzb[j];
            const float vnx = nxb[j];

            // publish step-t operands (CLOBBERS the weight staging region)
            lzr[lane] = zl;
            lza[lane] = fmaxf(zl, 0.f);     // relu ONCE per lane
            if (lane < DS) lup[lane] = ub[j];

            // emit z_t (carry BEFORE update; z[0] == z0)
            pz[0] = zl;

            float m0 = Ad * zl, m1 = 0.f, m2 = 0.f, m3 = 0.f;

            // u-dot: 4 broadcast ds_read_b128
            #pragma unroll
            for (int s4 = 0; s4 < 4; ++s4) {
                const float4 uu = *(const float4*)&lup[4 * s4];
                FMA_ASM(m0, Crow[4*s4+0], uu.x);
                FMA_ASM(m1, Crow[4*s4+1], uu.y);
                FMA_ASM(m2, Crow[4*s4+2], uu.z);
                FMA_ASM(m3, Crow[4*s4+3], uu.w);
            }

            // refill prefetch. Pointer rests on the LAST valid step (TT-1):
            // advance only while the NEXT prefetch target (t+5) is < TT.
            {
                const bool ok = (t + 5) < TT;
                nzb[j] = pnz_pf[0];
                nxb[j] = pnx_pf[0];
                ub[j]  = puu_pf[0];
                pnz_pf = ok ? (pnz_pf + snz) : pnz_pf;
                pnx_pf = ok ? (pnx_pf + snx) : pnx_pf;
                puu_pf = ok ? (puu_pf + su ) : puu_pf;
            }

            // W-dot: 16 broadcast ds_read_b128 of relu(z)
            #pragma unroll
            for (int k4 = 0; k4 < 16; ++k4) {
                const float4 zz = *(const float4*)&lza[4 * k4];
                FMA_ASM(m0, Wrow[4*k4+0], zz.x);
                FMA_ASM(m1, Wrow[4*k4+1], zz.y);
                FMA_ASM(m2, Wrow[4*k4+2], zz.z);
                FMA_ASM(m3, Wrow[4*k4+3], zz.w);
            }

            // x-dot: split-k (each half-wave does 32 of 64 k's)
            float xa0 = 0.f, xa1 = 0.f;
            #pragma unroll
            for (int k4 = 0; k4 < 8; ++k4) {
                const float4 zz = *(const float4*)&lzr[kb + 4 * k4];
                FMA_ASM(xa0, Brow[4*k4+0], zz.x);
                FMA_ASM(xa1, Brow[4*k4+1], zz.y);
                FMA_ASM(xa0, Brow[4*k4+2], zz.z);
                FMA_ASM(xa1, Brow[4*k4+3], zz.w);
            }
            float xs = xa0 + xa1;
            xs += __shfl_xor(xs, 32);       // combine k-halves
            if (lane < DX) px[0] = fmaf(vnx, rv, xs);

            pz += snz;
            px += snx;

            // z_{t+1} = mu + nz*q
            zl = fmaf(vnz, qv, (m0 + m1) + (m2 + m3));
        }
    }
}

extern "C" void kernel_launch(void* const* d_in, const int* in_sizes, int n_in,
                              void* d_out, int out_size, void* d_ws, size_t ws_size,
                              hipStream_t stream) {
    const float* u_  = (const float*)d_in[0];
    const float* z0_ = (const float*)d_in[1];
    const float* nz_ = (const float*)d_in[2];
    const float* nx_ = (const float*)d_in[3];
    const float* AW_ = (const float*)d_in[4];
    const float* C_  = (const float*)d_in[5];
    const float* B_  = (const float*)d_in[6];
    const float* Q_  = (const float*)d_in[7];
    const float* R_  = (const float*)d_in[8];

    float* zo = (float*)d_out;                 // (T,N,64) first
    float* xo = zo + (size_t)TT * NS * DZ;     // then (T,N,32)

    hipLaunchKernelGGL(plrnn_fused_kernel, dim3(NS / 4), dim3(256), 0, stream,
                       u_, z0_, nz_, nx_, AW_, C_, B_, Q_, R_, zo, xo);
}

// Round 11
// 716.539 us; speedup vs baseline: 1.2780x; 1.2780x over previous
//
#include <hip/hip_runtime.h>

#define DZ 64
#define DX 32
#define DS 16
#define TT 1024
#define NS 1024

// LDS: weight staging only. The hot loop performs ONE volatile ds_write per
// step into an aliasing region -> (a) store can't be dead-code'd, (b) weight
// re-reads from LDS become unsound -> weights must stay register-resident.
#define AW_B 0                           // 64 rows * 65
#define C_B  (AW_B + DZ * (DZ + 1))      // 64 * 17
#define B_B  (C_B + DZ * (DS + 1))       // 32 * 65
#define SMEM_FLOATS (B_B + DX * (DZ + 1))
#define ZR_B 0                           // clobber slots [4][64], alias AW rows

__device__ __forceinline__ float softplus_eps(float x) {
    // jax.nn.softplus = max(x,0) + log1p(exp(-|x|)); +1e-6
    return fmaxf(x, 0.f) + log1pf(expf(-fabsf(x))) + 1e-6f;
}

__global__ __launch_bounds__(256, 1) void plrnn_fused_kernel(
    const float* __restrict__ u,   // (T, N, 16)
    const float* __restrict__ z0,  // (N, 64)
    const float* __restrict__ nz,  // (T, N, 64)
    const float* __restrict__ nx,  // (T, N, 32)
    const float* __restrict__ AW,  // (64, 64)
    const float* __restrict__ Cm,  // (64, 16)
    const float* __restrict__ Bm,  // (32, 64)
    const float* __restrict__ Q,   // (64,)
    const float* __restrict__ R,   // (32,)
    float* __restrict__ zo,        // (T, N, 64)
    float* __restrict__ xo)        // (T, N, 32)
{
    const int tid  = threadIdx.x;
    const int lane = tid & 63;
    const int wv   = tid >> 6;
    const int p    = lane & 31;          // x output row (hi half duplicates)
    const int sim  = __builtin_amdgcn_readfirstlane((int)((blockIdx.x << 2) | wv));

    __shared__ float smem[SMEM_FLOATS];

    {   // one-time stage: AW 16/thr, C 4/thr, B 8/thr
        const int r = tid >> 2;
        const int c = (tid & 3) * 16;
        #pragma unroll
        for (int k = 0; k < 16; ++k) smem[AW_B + r * (DZ + 1) + c + k] = AW[r * DZ + c + k];
        const int cc = (tid & 3) * 4;
        #pragma unroll
        for (int k = 0; k < 4; ++k) smem[C_B + r * (DS + 1) + cc + k] = Cm[r * DS + cc + k];
        const int br = tid >> 3;
        const int bc = (tid & 7) * 8;
        #pragma unroll
        for (int k = 0; k < 8; ++k) smem[B_B + br * (DZ + 1) + bc + k] = Bm[br * DZ + bc + k];
    }
    __syncthreads();

    // per-lane weights -> registers (compile-time indices only)
    float Wrow[DZ];
    float Ad = 0.f;
    #pragma unroll
    for (int k = 0; k < DZ; ++k) {
        const float w = smem[AW_B + lane * (DZ + 1) + k];
        Wrow[k] = (k == lane) ? 0.f : w;    // zero diagonal
        Ad      = (k == lane) ? w   : Ad;   // capture diagonal
    }
    float Crow[DS];
    #pragma unroll
    for (int s = 0; s < DS; ++s) Crow[s] = smem[C_B + lane * (DS + 1) + s];
    float Brow[DZ];                          // FULL row: B[p][0..63]
    #pragma unroll
    for (int k = 0; k < DZ; ++k) Brow[k] = smem[B_B + p * (DZ + 1) + k];

    const float qv = softplus_eps(Q[lane]);
    const float rv = softplus_eps(R[p]);

    __syncthreads();   // all waves done reading staged weights before clobber

    float zl = z0[(size_t)sim * DZ + lane];

    const size_t snz = (size_t)NS * DZ;
    const size_t snx = (size_t)NS * DX;
    const size_t su  = (size_t)NS * DS;

    const float* pnz = nz + (size_t)sim * DZ + lane;
    const float* pnx = nx + (size_t)sim * DX + p;
    const float* puu = u  + (size_t)sim * DS + (lane & 15);
    float* pz = zo + (size_t)sim * DZ + lane;
    float* px = xo + (size_t)sim * DX + p;

    // prefetch depth 4, then running pointers with freeze-clamp (R8-proven)
    float nzb[4], nxb[4], ub[4];
    #pragma unroll
    for (int j = 0; j < 4; ++j) {
        nzb[j] = pnz[(size_t)j * snz];
        nxb[j] = pnx[(size_t)j * snx];
        ub[j]  = puu[(size_t)j * su];
    }
    const float* pnz_pf = pnz + 4 * snz;
    const float* pnx_pf = pnx + 4 * snx;
    const float* puu_pf = puu + 4 * su;

    volatile float* lclob = &smem[ZR_B + wv * DZ];   // wave-private clobber slot

    for (int t0 = 0; t0 < TT; t0 += 4) {
        #pragma unroll
        for (int j = 0; j < 4; ++j) {
            const int t = t0 + j;
            const float vnz = nzb[j];
            const float vnx = nxb[j];

            // anti-remat clobber: one volatile ds_write aliasing the staging
            lclob[lane] = zl;

            // emit z_t (carry BEFORE update; z[0] == z0)
            pz[0] = zl;

            const int zraw = __float_as_int(zl);
            const int uraw = __float_as_int(ub[j]);

            float m0 = Ad * zl, m1 = 0.f, m2 = 0.f, m3 = 0.f;
            float xa0 = 0.f, xa1 = 0.f, xa2 = 0.f, xa3 = 0.f;

            // u-dot: broadcast u via readlane (lanes 0-15 hold u[0..15])
            #pragma unroll
            for (int c = 0; c < DS; c += 4) {
                int sg0 = __builtin_amdgcn_readlane(uraw, c + 0);
                int sg1 = __builtin_amdgcn_readlane(uraw, c + 1);
                int sg2 = __builtin_amdgcn_readlane(uraw, c + 2);
                int sg3 = __builtin_amdgcn_readlane(uraw, c + 3);
                m0 = fmaf(Crow[c + 0], __int_as_float(sg0), m0);
                m1 = fmaf(Crow[c + 1], __int_as_float(sg1), m1);
                m2 = fmaf(Crow[c + 2], __int_as_float(sg2), m2);
                m3 = fmaf(Crow[c + 3], __int_as_float(sg3), m3);
            }

            // refill prefetch; pointer freeze-clamp (advance while t+5 < TT)
            {
                const bool ok = (t + 5) < TT;
                nzb[j] = pnz_pf[0];
                nxb[j] = pnx_pf[0];
                ub[j]  = puu_pf[0];
                pnz_pf = ok ? (pnz_pf + snz) : pnz_pf;
                pnx_pf = ok ? (pnx_pf + snx) : pnx_pf;
                puu_pf = ok ? (puu_pf + su ) : puu_pf;
            }

            // combined W-dot (relu) + x-dot (raw): ONE readlane per k feeds
            // both. All-VALU broadcast - zero shared-DS-pipe traffic.
            #pragma unroll
            for (int c = 0; c < DZ; c += 8) {
                int sg[8];
                #pragma unroll
                for (int i = 0; i < 8; ++i)
                    sg[i] = __builtin_amdgcn_readlane(zraw, c + i);
                #pragma unroll
                for (int i = 0; i < 8; ++i) {
                    const int k = c + i;
                    const float zk = __int_as_float(sg[i]);
                    const float rk = fmaxf(zk, 0.f);   // relu of broadcast
                    if ((i & 3) == 0) { m0 = fmaf(Wrow[k], rk, m0); xa0 = fmaf(Brow[k], zk, xa0); }
                    if ((i & 3) == 1) { m1 = fmaf(Wrow[k], rk, m1); xa1 = fmaf(Brow[k], zk, xa1); }
                    if ((i & 3) == 2) { m2 = fmaf(Wrow[k], rk, m2); xa2 = fmaf(Brow[k], zk, xa2); }
                    if ((i & 3) == 3) { m3 = fmaf(Wrow[k], rk, m3); xa3 = fmaf(Brow[k], zk, xa3); }
                }
            }

            // x_t = z_t @ B.T + nx*r (hi half duplicates; low half stores)
            const float xs = (xa0 + xa1) + (xa2 + xa3);
            if (lane < DX) px[0] = fmaf(vnx, rv, xs);

            pz += snz;
            px += snx;

            // z_{t+1} = mu + nz*q
            zl = fmaf(vnz, qv, (m0 + m1) + (m2 + m3));
        }
    }
}

extern "C" void kernel_launch(void* const* d_in, const int* in_sizes, int n_in,
                              void* d_out, int out_size, void* d_ws, size_t ws_size,
                              hipStream_t stream) {
    const float* u_  = (const float*)d_in[0];
    const float* z0_ = (const float*)d_in[1];
    const float* nz_ = (const float*)d_in[2];
    const float* nx_ = (const float*)d_in[3];
    const float* AW_ = (const float*)d_in[4];
    const float* C_  = (const float*)d_in[5];
    const float* B_  = (const float*)d_in[6];
    const float* Q_  = (const float*)d_in[7];
    const float* R_  = (const float*)d_in[8];

    float* zo = (float*)d_out;                 // (T,N,64) first
    float* xo = zo + (size_t)TT * NS * DZ;     // then (T,N,32)

    hipLaunchKernelGGL(plrnn_fused_kernel, dim3(NS / 4), dim3(256), 0, stream,
                       u_, z0_, nz_, nx_, AW_, C_, B_, Q_, R_, zo, xo);
}

// Round 12
// 456.828 us; speedup vs baseline: 2.0045x; 1.5685x over previous
//
#include <hip/hip_runtime.h>

#define DZ 64
#define DX 32
#define DS 16
#define TT 1024
#define NS 1024
#define SNZ (NS * DZ)
#define SNX (NS * DX)
#define SU4 (NS * DS / 4)     // per-step stride in float4 units (u)

// ---- LDS layout (floats) ----
// staging (read once into registers):
#define AW_B 0
#define C_B  (AW_B + DZ * (DZ + 1))
#define B_B  (C_B + DZ * (DS + 1))
#define SMEM_FLOATS (B_B + DX * (DZ + 1))   // 7328 floats = 29.3 KB
// runtime overlay ALIASES the staging region (anti-remat clobber, R8-proven):
#define ZR_O 0                 // raw z_t      [64]
#define RZ_O DZ                // relu z_t     [64]
#define PM_O (2 * DZ)          // mu partials  [parity 2][kh 2][64]
#define PX_O (2 * DZ + 256)    // x partials   [parity 2][32] (wave0's half)

__device__ __forceinline__ float softplus_eps(float x) {
    // jax.nn.softplus = max(x,0) + log1p(exp(-|x|)); +1e-6
    return fmaxf(x, 0.f) + log1pf(expf(-fabsf(x))) + 1e-6f;
}

// 2 waves per sim (k-halves), 1024 blocks x 128 threads = 2048 waves
// -> 2 waves/SIMD (TLP at last). One __syncthreads per step; partial
// arrays parity-double-buffered; both waves recompute z' bit-identically.
__global__ __launch_bounds__(128, 2) void plrnn_split_kernel(
    const float* __restrict__ u,   // (T, N, 16)
    const float* __restrict__ z0,  // (N, 64)
    const float* __restrict__ nz,  // (T, N, 64)
    const float* __restrict__ nx,  // (T, N, 32)
    const float* __restrict__ AW,  // (64, 64)
    const float* __restrict__ Cm,  // (64, 16)
    const float* __restrict__ Bm,  // (32, 64)
    const float* __restrict__ Q,   // (64,)
    const float* __restrict__ R,   // (32,)
    float* __restrict__ zo,        // (T, N, 64)
    float* __restrict__ xo)        // (T, N, 32)
{
    const int tid  = threadIdx.x;
    const int lane = tid & 63;
    const int kh   = tid >> 6;            // k-half: 0 or 1 (wave id in block)
    const int p    = lane & 31;           // x output row
    const int sim  = __builtin_amdgcn_readfirstlane((int)blockIdx.x);

    __shared__ float smem[SMEM_FLOATS];

    {   // one-time stage (128 threads): AW 32/thr, C 8/thr, B 16/thr
        const int r = tid >> 1;
        const int c = (tid & 1) * 32;
        #pragma unroll
        for (int k = 0; k < 32; ++k) smem[AW_B + r * (DZ + 1) + c + k] = AW[r * DZ + c + k];
        const int cc = (tid & 1) * 8;
        #pragma unroll
        for (int k = 0; k < 8; ++k) smem[C_B + r * (DS + 1) + cc + k] = Cm[r * DS + cc + k];
        const int br = tid >> 2;
        const int bc = (tid & 3) * 16;
        #pragma unroll
        for (int k = 0; k < 16; ++k) smem[B_B + br * (DZ + 1) + bc + k] = Bm[br * DZ + bc + k];
    }
    __syncthreads();

    // per-lane weight slices -> registers (compile-time reg indices only)
    float Wrow[32];                       // W_off[lane][32kh .. 32kh+31]
    #pragma unroll
    for (int j = 0; j < 32; ++j) {
        const int k = 32 * kh + j;
        const float w = smem[AW_B + lane * (DZ + 1) + k];
        Wrow[j] = (k == lane) ? 0.f : w;  // zero diagonal (select, not reg-index)
    }
    const float Ad = smem[AW_B + lane * (DZ + 1) + lane];   // runtime LDS read: fine
    float Crow[8];                        // C[lane][8kh .. 8kh+7]
    #pragma unroll
    for (int j = 0; j < 8; ++j) Crow[j] = smem[C_B + lane * (DS + 1) + 8 * kh + j];
    const int kq = 32 * kh + ((lane >> 5) << 4);   // 16-k quarter for x
    float Brow[16];                       // B[p][kq .. kq+15]
    #pragma unroll
    for (int j = 0; j < 16; ++j) Brow[j] = smem[B_B + p * (DZ + 1) + kq + j];

    const float qv = softplus_eps(Q[lane]);
    const float rv = softplus_eps(R[p]);

    __syncthreads();   // staging reads done before runtime overlay clobbers it

    float zl = z0[sim * DZ + lane];       // both waves: identical copy of z_t

    // uniform bases (SGPR) + small int indices -> scalar-friendly addressing
    const float*  nzb = nz + sim * DZ;
    const float*  nxb = nx + sim * DX;
    const float4* ub4 = (const float4*)(u + sim * DS + 8 * kh);  // wave's 8 u's
    float* zob = zo + sim * DZ;
    float* xob = xo + sim * DX;

    // prefetch depth 4, index-clamped (R3-proven safe at the tail)
    float nzp[4], nxp[4];
    float4 upA[4], upB[4];
    #pragma unroll
    for (int j = 0; j < 4; ++j) {
        nzp[j] = nzb[lane + j * SNZ];
        nxp[j] = nxb[p + j * SNX];
        upA[j] = ub4[j * SU4];
        upB[j] = ub4[j * SU4 + 1];
    }

    for (int t0 = 0; t0 < TT; t0 += 4) {
        #pragma unroll
        for (int j = 0; j < 4; ++j) {
            const int t   = t0 + j;
            const int par = j & 1;        // parity (compile-time per j)
            const float  vnz = nzp[j];
            const float  vnx = nxp[j];
            const float4 ua  = upA[j];
            const float4 ubv = upB[j];

            // ---- phase 1: publish z_t broadcast (both waves, identical bits)
            smem[ZR_O + lane] = zl;
            smem[RZ_O + lane] = fmaxf(zl, 0.f);
            if (kh == 0) zob[lane + t * SNZ] = zl;   // emit z_t (pre-update)

            // u-dot (register operands, fills LDS latency shadow)
            float m0 = Crow[0] * ua.x,  m1 = Crow[1] * ua.y;
            float m2 = Crow[2] * ua.z,  m3 = Crow[3] * ua.w;
            m0 = fmaf(Crow[4], ubv.x, m0); m1 = fmaf(Crow[5], ubv.y, m1);
            m2 = fmaf(Crow[6], ubv.z, m2); m3 = fmaf(Crow[7], ubv.w, m3);

            // refill prefetch (clamped; tail values loaded but unused)
            {
                int tn = t + 4; tn = (tn < TT) ? tn : (TT - 1);
                nzp[j] = nzb[lane + tn * SNZ];
                nxp[j] = nxb[p + tn * SNX];
                upA[j] = ub4[tn * SU4];
                upB[j] = ub4[tn * SU4 + 1];
            }

            // W-half dot: 8 broadcast ds_read_b128 of relu(z_t)
            #pragma unroll
            for (int k4 = 0; k4 < 8; ++k4) {
                const float4 zz = *(const float4*)&smem[RZ_O + 32 * kh + 4 * k4];
                m0 = fmaf(Wrow[4 * k4 + 0], zz.x, m0);
                m1 = fmaf(Wrow[4 * k4 + 1], zz.y, m1);
                m2 = fmaf(Wrow[4 * k4 + 2], zz.z, m2);
                m3 = fmaf(Wrow[4 * k4 + 3], zz.w, m3);
            }

            // x-quarter dot: 4 broadcast ds_read_b128 of raw z_t
            float xa0 = 0.f, xa1 = 0.f;
            #pragma unroll
            for (int k4 = 0; k4 < 4; ++k4) {
                const float4 zz = *(const float4*)&smem[ZR_O + kq + 4 * k4];
                xa0 = fmaf(Brow[4 * k4 + 0], zz.x, xa0);
                xa1 = fmaf(Brow[4 * k4 + 1], zz.y, xa1);
                xa0 = fmaf(Brow[4 * k4 + 2], zz.z, xa0);
                xa1 = fmaf(Brow[4 * k4 + 3], zz.w, xa1);
            }
            float xpart = xa0 + xa1;
            xpart += __shfl_xor(xpart, 32);   // merge the two 16-k quarters

            const float mown = (m0 + m1) + (m2 + m3);
            smem[PM_O + par * 128 + kh * 64 + lane] = mown;
            if (kh == 0 && lane < 32) smem[PX_O + par * 32 + p] = xpart;

            __syncthreads();   // the ONE barrier per step

            // ---- phase 2: combine partials
            const float moth = smem[PM_O + par * 128 + (1 - kh) * 64 + lane];
            // kh-independent operand order -> both waves' z' are bit-identical
            const float h0 = (kh == 0) ? mown : moth;
            const float h1 = (kh == 0) ? moth : mown;

            if (kh == 1 && lane < 32) {      // wave1 finishes + stores x_t
                const float xoth = smem[PX_O + par * 32 + p];
                xob[p + t * SNX] = fmaf(vnx, rv, xpart + xoth);
            }

            // z_{t+1} = A_diag*z + (half0 + half1) + q*nz
            zl = fmaf(qv, vnz, fmaf(Ad, zl, h0 + h1));
        }
    }
}

extern "C" void kernel_launch(void* const* d_in, const int* in_sizes, int n_in,
                              void* d_out, int out_size, void* d_ws, size_t ws_size,
                              hipStream_t stream) {
    const float* u_  = (const float*)d_in[0];
    const float* z0_ = (const float*)d_in[1];
    const float* nz_ = (const float*)d_in[2];
    const float* nx_ = (const float*)d_in[3];
    const float* AW_ = (const float*)d_in[4];
    const float* C_  = (const float*)d_in[5];
    const float* B_  = (const float*)d_in[6];
    const float* Q_  = (const float*)d_in[7];
    const float* R_  = (const float*)d_in[8];

    float* zo = (float*)d_out;                 // (T,N,64) first
    float* xo = zo + (size_t)TT * NS * DZ;     // then (T,N,32)

    hipLaunchKernelGGL(plrnn_split_kernel, dim3(NS), dim3(128), 0, stream,
                       u_, z0_, nz_, nx_, AW_, C_, B_, Q_, R_, zo, xo);
}